// Round 3
// baseline (1534.068 us; speedup 1.0000x reference)
//
#include <hip/hip_runtime.h>
#include <hip/hip_bf16.h>

typedef __bf16 bf16;
typedef __bf16 bf16x8 __attribute__((ext_vector_type(8)));
typedef __bf16 bf16x4 __attribute__((ext_vector_type(4)));
typedef float  f32x4  __attribute__((ext_vector_type(4)));
typedef unsigned int u32;

// ---------------- workspace layout (bytes), peak 120MB ----------------
#define OFF_BNSUM 0u
#define OFF_BNSQ  (32u<<10)
#define OFF_HBUF  (64u<<10)                       // 2 parity * 16 grp * 16 * 512 f32 = 1MB
#define OFF_CNT   ((64u<<10) + (1u<<20))          // 16 counters, 256B stride
#define ZERO_END  ((64u<<10) + (1u<<20) + 4096u)
#define OFF_XNP   (3u<<20)                        // xn packed frags bf16, 4MB
#define OFF_P     (8u<<20)                        // gemm1 partials 4*8MB (dead after k_attn)
#define OFF_HS    (8u<<20)                        // hs bf16 [256][64][512] 16MB (reuses P)
#define OFF_BPART (24u<<20)                       // beta partials f32 4MB (reuses P)
#define OFF_GATP  (40u<<20)                       // gated packed frags bf16 4MB
#define OFF_WIH   (44u<<20)                       // W_ih bf16 swizzled 512KB
#define OFF_WHH   (45u<<20)                       // W_hh packed frags bf16 2MB
#define OFF_BIAS2 (47u<<20)                       // b_ih+b_hh f32 8KB
#define OFF_WTA   (48u<<20)                       // W_ta bf16 4MB
#define OFF_WOT   (52u<<20)                       // W_out^T bf16 128KB
#define OFF_GX    (56u<<20)                       // gates_x packed bf16 64MB

__device__ __forceinline__ float sigf(float x){ return 1.0f/(1.0f+__expf(-x)); }
__device__ __forceinline__ float tanhf_(float x){
  x = fminf(fmaxf(x,-15.f),15.f);
  float e = __expf(2.f*x);
  return (e-1.f)/(e+1.f);
}
__device__ __forceinline__ f32x4 mfma16(bf16x8 a, bf16x8 b, f32x4 c){
  return __builtin_amdgcn_mfma_f32_16x16x32_bf16(a, b, c, 0, 0, 0);
}

// ---------------- prep: weight packing + BN partial stats ----------------
// blocks [0,1704): thread-ranges A..E below; blocks [1704,1960): BN stats
// A: W_hh -> frag-packed bf16 [s16][nt8][kt16][lane64][8]
// B: W_ih -> bf16, XOR-swizzled rows [2048][128]
// C: W_ta -> bf16 linear
// D: W_out -> W_out^T bf16 [512][128]
// E: bias2 = b_ih + b_hh
__global__ void k_prep(const float* __restrict__ Whh, const float* __restrict__ Wih,
                       const float* __restrict__ Wta, const float* __restrict__ Wout,
                       const float* __restrict__ bih, const float* __restrict__ bhh,
                       const float* __restrict__ input, char* __restrict__ ws) {
  if (blockIdx.x >= 1704) {             // BN partial stats
    int bxx = blockIdx.x - 1704;        // 256 blocks
    int col = (bxx >> 3)*256 + threadIdx.x;
    int r0 = (bxx & 7)*32;
    float s=0.f, s2=0.f;
    for (int r=0;r<32;r++){ float v = input[(size_t)(r0+r)*8192 + col]; s+=v; s2+=v*v; }
    float* wsf = (float*)ws;
    atomicAdd(&wsf[col], s);
    atomicAdd(&wsf[8192 + col], s2);
    return;
  }
  int tid = blockIdx.x*256 + threadIdx.x;
  if (tid < 16*8*16*64) {               // A: 131072 packs
    int l = tid & 63, kt = (tid>>6)&15, nt = (tid>>10)&7, s = tid>>13;
    int gate = nt>>1, c16 = nt&1;
    int n = gate*512 + s*32 + c16*16 + (l&15);
    int k0 = kt*32 + ((l>>4)<<3);
    const float* src = Whh + (size_t)n*512 + k0;
    bf16x8 v;
    #pragma unroll
    for (int j=0;j<8;j++) v[j] = (bf16)src[j];
    *(bf16x8*)(ws + OFF_WHH + (size_t)tid*16) = v;
    return;
  }
  int t2 = tid - 16*8*16*64;
  if (t2 < 2048*16) {                   // B: 32768 packs of 8
    int n = t2 >> 4, kq = t2 & 15; int k0 = kq*8;
    const float* src = Wih + (size_t)n*128 + k0;
    bf16x8 v;
    #pragma unroll
    for (int j=0;j<8;j++) v[j] = (bf16)src[j];
    u32 byte = (u32)(n*256) + (((u32)(k0*2)) ^ (((u32)(n&7))<<4));
    *(bf16x8*)(ws + OFF_WIH + byte) = v;
    return;
  }
  int t3 = t2 - 2048*16;
  if (t3 < 262144) {                    // C
    const float* src = Wta + (size_t)t3*8;
    bf16x8 v;
    #pragma unroll
    for (int j=0;j<8;j++) v[j] = (bf16)src[j];
    *(bf16x8*)(ws + OFF_WTA + (size_t)t3*16) = v;
    return;
  }
  int t4 = t3 - 262144;
  if (t4 < 512*16) {                    // D
    int j = t4 >> 4, oq = t4 & 15; int o0 = oq*8;
    bf16x8 v;
    #pragma unroll
    for (int jj=0;jj<8;jj++) v[jj] = (bf16)Wout[(size_t)(o0+jj)*512 + j];
    *(bf16x8*)(ws + OFF_WOT + (size_t)t4*16) = v;
    return;
  }
  int t5 = t4 - 8192;
  if (t5 < 2048) {                      // E
    ((float*)(ws + OFF_BIAS2))[t5] = bih[t5] + bhh[t5];
  }
}

// ---------------- xn = BN(input), packed into A-fragment layout ----------------
// derives scale/shift inline from partial sums (BN finalize fused)
// xnp idx = ((mt*256 + kt)*64 + l) ; elem m = mt*16+(l&15), k = kt*32+(l>>4)*8+j
__global__ void k_xnpack(const float* __restrict__ in, const float* __restrict__ gamma,
                         const float* __restrict__ betaP, char* __restrict__ ws) {
  int idx = blockIdx.x*256 + threadIdx.x;   // 262144 items, grid 1024
  int l = idx & 63, kt = (idx>>6)&255, mt = idx>>14;
  int m = mt*16 + (l&15), k0 = kt*32 + ((l>>4)<<3);
  const float* sums = (const float*)(ws + OFF_BNSUM);
  const float* sqs  = (const float*)(ws + OFF_BNSQ);
  const float* src = in + (size_t)m*8192 + k0;
  bf16x8 v;
  #pragma unroll
  for (int j=0;j<8;j++) {
    int k = k0 + j;
    float mu = sums[k] * (1.f/256.f);
    float q  = sqs[k]  * (1.f/256.f);
    float rstd = rsqrtf(q - mu*mu + 1e-5f);
    float sc = rstd * gamma[k];
    v[j] = (bf16)(src[j]*sc + (betaP[k] - mu*sc));
  }
  *(bf16x8*)(ws + OFF_XNP + (size_t)idx*16) = v;
}

// ---------------- GEMM1: out1 = xn @ W_in.T  (M=256,N=8192,K=8192) ----------------
// grid (64 nb, 4 ks), block 512 (8 waves, 4Mx2N of 64x64 wave tiles), BK=64, dbuf LDS B
__global__ __launch_bounds__(512,2) void k_gemm1(const float* __restrict__ Win,
                                                 char* __restrict__ ws) {
  __shared__ __align__(16) char lds[2*16384];
  const int nb = blockIdx.x, ks = blockIdx.y;
  const int tid = threadIdx.x, l = tid & 63, w = tid >> 6;
  const int wm = w >> 1, wn = w & 1;
  const char* xnp = ws + OFF_XNP;
  f32x4 z = {0.f,0.f,0.f,0.f};
  f32x4 acc[4][4];
  #pragma unroll
  for (int i=0;i<4;i++){ acc[i][0]=z; acc[i][1]=z; acc[i][2]=z; acc[i][3]=z; }

  const int r = tid >> 2, kc = (tid & 3) << 4;
  const float* bsrc = Win + (size_t)(nb*128 + r)*8192 + ks*2048 + kc;
  const u32 sw = ((u32)(r&7))<<4;
  const u32 bdst0 = (u32)(r*128) + (((u32)(kc*2))     ^ sw);
  const u32 bdst1 = (u32)(r*128) + (((u32)(kc*2+16))  ^ sw);

  { // prologue stage step0
    f32x4 t0 = *(const f32x4*)(bsrc+0);
    f32x4 t1 = *(const f32x4*)(bsrc+4);
    f32x4 t2 = *(const f32x4*)(bsrc+8);
    f32x4 t3 = *(const f32x4*)(bsrc+12);
    bf16x8 p0,p1;
    #pragma unroll
    for(int j=0;j<4;j++){ p0[j]=(bf16)t0[j]; p0[4+j]=(bf16)t1[j]; p1[j]=(bf16)t2[j]; p1[4+j]=(bf16)t3[j]; }
    *(bf16x8*)(lds + bdst0) = p0;
    *(bf16x8*)(lds + bdst1) = p1;
  }
  int cur = 0;
  for (int s=0; s<32; s++) {
    f32x4 t0,t1,t2,t3;
    const bool more = (s+1) < 32;
    if (more) {
      const float* p = bsrc + (s+1)*64;
      t0 = *(const f32x4*)(p+0); t1 = *(const f32x4*)(p+4);
      t2 = *(const f32x4*)(p+8); t3 = *(const f32x4*)(p+12);
    }
    bf16x8 af[4][2];
    #pragma unroll
    for (int i=0;i<4;i++)
      #pragma unroll
      for (int kk=0;kk<2;kk++) {
        int mt = wm*4 + i;
        int ktg = ks*64 + s*2 + kk;
        af[i][kk] = *(const bf16x8*)(xnp + ((size_t)(mt*256 + ktg)*64 + l)*16);
      }
    __syncthreads();
    const char* buf = lds + cur*16384;
    bf16x8 bfr[4][2];
    #pragma unroll
    for (int j=0;j<4;j++)
      #pragma unroll
      for (int kk=0;kk<2;kk++) {
        int n = (wn*4 + j)*16 + (l&15);
        u32 byte = (u32)(n*128) + (((u32)(kk*64 + ((l>>4)<<4))) ^ (((u32)(n&7))<<4));
        bfr[j][kk] = *(const bf16x8*)(buf + byte);
      }
    #pragma unroll
    for (int kk=0;kk<2;kk++)
      #pragma unroll
      for (int i=0;i<4;i++)
        #pragma unroll
        for (int j=0;j<4;j++)
          acc[i][j] = mfma16(af[i][kk], bfr[j][kk], acc[i][j]);
    if (more) {
      bf16x8 p0,p1;
      #pragma unroll
      for(int j=0;j<4;j++){ p0[j]=(bf16)t0[j]; p0[4+j]=(bf16)t1[j]; p1[j]=(bf16)t2[j]; p1[4+j]=(bf16)t3[j]; }
      char* obuf = lds + (cur^1)*16384;
      *(bf16x8*)(obuf + bdst0) = p0;
      *(bf16x8*)(obuf + bdst1) = p1;
      cur ^= 1;
    }
  }
  float* outp = (float*)(ws + OFF_P) + (size_t)ks*256*8192;
  #pragma unroll
  for (int i=0;i<4;i++)
    #pragma unroll
    for (int j=0;j<4;j++)
      #pragma unroll
      for (int rr=0;rr<4;rr++) {
        int m = wm*64 + i*16 + (l>>4)*4 + rr;
        int n = nb*128 + (wn*4+j)*16 + (l&15);
        outp[(size_t)m*8192 + n] = acc[i][j][rr];
      }
}

// ---------------- spatial attention (+split-K reduce fused) -> gated, packed ----------------
// grid (64 t, 16 bg), block 256
__global__ __launch_bounds__(256) void k_attn(const float* __restrict__ Wsa,
                                              const float* __restrict__ bsa,
                                              char* __restrict__ ws) {
  __shared__ __align__(16) bf16 WsaT[128*128];   // [d][e] bf16, 32KB
  __shared__ __align__(16) float xrow[16*128];   // 8KB
  __shared__ __align__(16) bf16  gat[16*128];    // 4KB
  int t = blockIdx.x, bg = blockIdx.y;
  int tid = threadIdx.x, l = tid & 63, w = tid >> 6;
  for (int i = tid; i < 128*32; i += 256) {
    int e = i >> 5, dq = i & 31;
    f32x4 v = *(const f32x4*)(Wsa + (size_t)e*128 + dq*4);
    #pragma unroll
    for (int j=0;j<4;j++) WsaT[(dq*4+j)*128 + e] = (bf16)v[j];
  }
  const float* p0 = (const float*)(ws + OFF_P);
  const size_t SLAB = (size_t)256*8192;   // gemm1 partial slab stride, in floats (8MB)
  for (int i = tid; i < 16*32; i += 256) {
    int rb = i >> 5, dq = i & 31;
    size_t off = (size_t)(bg*16 + rb)*8192 + t*128 + dq*4;
    f32x4 v = *(const f32x4*)(p0 + off);
    v = v + *(const f32x4*)(p0 + SLAB   + off);
    v = v + *(const f32x4*)(p0 + 2*SLAB + off);
    v = v + *(const f32x4*)(p0 + 3*SLAB + off);
    *(f32x4*)(&xrow[rb*128 + dq*4]) = v;
  }
  __syncthreads();
  float b0 = bsa[l], b1 = bsa[64+l];
  for (int rb = w; rb < 16; rb += 4) {
    float a0 = b0, a1 = b1;
    const float* xr = &xrow[rb*128];
    #pragma unroll 4
    for (int d=0; d<128; d++) {
      float xv = xr[d];
      a0 += xv * (float)WsaT[d*128 + l];
      a1 += xv * (float)WsaT[d*128 + 64 + l];
    }
    a0 = sigf(a0); a1 = sigf(a1);
    float mx = fmaxf(a0,a1);
    #pragma unroll
    for (int o=32;o>0;o>>=1) mx = fmaxf(mx, __shfl_xor(mx,o));
    float e0 = __expf(a0-mx), e1 = __expf(a1-mx);
    float sm = e0+e1;
    #pragma unroll
    for (int o=32;o>0;o>>=1) sm += __shfl_xor(sm,o);
    float inv = 1.f/sm;
    gat[rb*128 + l]      = (bf16)(xr[l]     * e0*inv);
    gat[rb*128 + 64 + l] = (bf16)(xr[64+l]  * e1*inv);
  }
  __syncthreads();
  { // pack 16x128 tile into frag order
    int kt = tid >> 6;
    int m = l & 15, k0 = kt*32 + ((l>>4)<<3);
    bf16x8 v = *(const bf16x8*)(&gat[m*128 + k0]);
    *(bf16x8*)(ws + OFF_GATP + ((size_t)((t*16 + bg)*4 + kt)*64 + l)*16) = v;
  }
}

// ---------------- gates_x = gated @ W_ih.T, output in LSTM-consumable packed layout ----------------
// grid (256 mb = t*4+bq, 16 nb), block 256 (4 waves, 2Mx2N of 32x64)
__global__ __launch_bounds__(256) void k_gxgemm(char* __restrict__ ws) {
  __shared__ __align__(16) char ldsB[32768];
  int mb = blockIdx.x, nb = blockIdx.y;
  int t = mb >> 2, bq = mb & 3;
  int tid = threadIdx.x, l = tid & 63, w = tid >> 6;
  int wm = w >> 1, wn = w & 1;
  { // copy pre-swizzled W_ih slice (raw bytes)
    const f32x4* src = (const f32x4*)(ws + OFF_WIH + (size_t)nb*32768);
    f32x4* dst = (f32x4*)ldsB;
    for (int i = tid; i < 2048; i += 256) dst[i] = src[i];
  }
  __syncthreads();
  f32x4 z = {0.f,0.f,0.f,0.f};
  f32x4 acc[2][4];
  #pragma unroll
  for (int i=0;i<2;i++){ acc[i][0]=z; acc[i][1]=z; acc[i][2]=z; acc[i][3]=z; }
  const char* gatp = ws + OFF_GATP;
  #pragma unroll
  for (int kt=0; kt<4; kt++) {
    bf16x8 a[2], bb[4];
    #pragma unroll
    for (int i=0;i<2;i++) {
      int mtg = bq*4 + wm*2 + i;
      a[i] = *(const bf16x8*)(gatp + ((size_t)((t*16 + mtg)*4 + kt)*64 + l)*16);
    }
    #pragma unroll
    for (int j=0;j<4;j++) {
      int n = (wn*4 + j)*16 + (l&15);
      u32 byte = (u32)(n*256) + (((u32)(kt*64 + ((l>>4)<<4))) ^ (((u32)(n&7))<<4));
      bb[j] = *(const bf16x8*)(ldsB + byte);
    }
    #pragma unroll
    for (int i=0;i<2;i++)
      #pragma unroll
      for (int j=0;j<4;j++)
        acc[i][j] = mfma16(a[i], bb[j], acc[i][j]);
  }
  int gate = nb >> 2, q = nb & 3;
  #pragma unroll
  for (int i=0;i<2;i++)
    #pragma unroll
    for (int j=0;j<4;j++) {
      int ntl = wn*4 + j;
      int c16g = q*8 + ntl;
      int s = c16g >> 1, c16 = c16g & 1;
      int nt_out = gate*2 + c16;
      int mtg = bq*4 + wm*2 + i;           // == batch group
      bf16x4 pv;
      #pragma unroll
      for (int rr=0;rr<4;rr++) pv[rr] = (bf16)acc[i][j][rr];
      *(bf16x4*)(ws + OFF_GX + (((((size_t)mtg*64 + t)*16 + s)*8 + nt_out)*64 + l)*8) = pv;
    }
}

// ---------------- LSTM: 256 blocks = 16 groups x 16 H-slices; W_hh in VGPRs ----------------
// grp = bid&15 so each sync-group's 16 blocks share one XCD under round-robin
// bid->XCD assignment (locality only; correctness is mapping-independent).
__global__ __launch_bounds__(256,1) void k_lstm(char* __restrict__ ws) {
  __shared__ __align__(16) char hl[16*1024];   // h tile [16][512] bf16, XOR-swizzled
  __shared__ __align__(16) f32x4 xsc[512];     // cross-wave acc exchange
  const int bid = blockIdx.x;
  const int grp = bid & 15, s = bid >> 4;
  const int tid = threadIdx.x, l = tid & 63, w = tid >> 6;
  const int c16 = w & 1, kh = w >> 1;
  bf16x8 breg[4][8];
  {
    const char* wp = ws + OFF_WHH;
    #pragma unroll
    for (int g=0; g<4; g++) {
      int nt = g*2 + c16;
      #pragma unroll
      for (int j=0;j<8;j++) {
        int kt = kh*8 + j;
        breg[g][j] = *(const bf16x8*)(wp + ((size_t)((s*8 + nt)*16 + kt)*64 + l)*16);
      }
    }
  }
  float bias[4] = {0,0,0,0};
  if (w < 2) {
    const float* b2 = (const float*)(ws + OFF_BIAS2);
    #pragma unroll
    for (int g=0;g<4;g++) bias[g] = b2[g*512 + s*32 + c16*16 + (l&15)];
  }
  float c[4] = {0,0,0,0};
  u32* cnt = (u32*)(ws + OFF_CNT) + grp*64;
  float* hbuf = (float*)(ws + OFF_HBUF);
  const int HB = 16*16*512;
  const int lrow = tid >> 4, lcol0 = (tid & 15) << 5;   // for hbuf->LDS fill
  const char* gx = ws + OFF_GX;

  for (int t=0; t<64; t++) {
    // gx fragments are immutable inputs: issue loads BEFORE the sync so their
    // latency hides under the spin/fence (values land in regs; fence only
    // invalidates caches, not registers)
    bf16x4 gxa[4];
    if (w < 2) {
      #pragma unroll
      for (int g=0;g<4;g++) {
        int nt = g*2 + c16;
        gxa[g] = *(const bf16x4*)(gx + (((((size_t)grp*64 + t)*16 + s)*8 + nt)*64 + l)*8);
      }
    }
    if (t > 0) {
      if (tid == 0) {
        u32 target = (u32)(16*t);
        while (__hip_atomic_load(cnt, __ATOMIC_RELAXED, __HIP_MEMORY_SCOPE_AGENT) < target)
          __builtin_amdgcn_s_sleep(2);
      }
      __syncthreads();
      __builtin_amdgcn_fence(__ATOMIC_ACQUIRE, "agent");
    }
    { // fill LDS h tile (bf16, swizzled)
      const float* hsrc = hbuf + (size_t)(t&1)*HB + (size_t)grp*(16*512);
      const f32x4* sp = (const f32x4*)(hsrc + (size_t)lrow*512 + lcol0);
      u32 base = (u32)(lrow*1024);
      u32 swz = ((u32)(lrow&7)) << 4;
      #pragma unroll
      for (int i=0;i<8;i++) {
        f32x4 v = sp[i];
        bf16x4 pv;
        #pragma unroll
        for (int j=0;j<4;j++) pv[j] = (bf16)v[j];
        u32 byte = base + (((u32)((lcol0 + i*4)*2)) ^ swz);
        *(bf16x4*)(hl + byte) = pv;
      }
    }
    __syncthreads();
    f32x4 z = {0.f,0.f,0.f,0.f};
    f32x4 acc[4]; acc[0]=z; acc[1]=z; acc[2]=z; acc[3]=z;
    {
      bf16x8 af[8];
      u32 qof = ((u32)(l>>4)) << 4;
      int row = l & 15;
      u32 rsw = ((u32)(row&7))<<4;
      #pragma unroll
      for (int j=0;j<8;j++) {
        int kt = kh*8 + j;
        u32 byte = (u32)(row*1024) + ((((u32)(kt*64)) + qof) ^ rsw);
        af[j] = *(const bf16x8*)(hl + byte);
      }
      #pragma unroll
      for (int j=0;j<8;j++)
        #pragma unroll
        for (int g=0;g<4;g++)
          acc[g] = mfma16(af[j], breg[g][j], acc[g]);
    }
    if (w >= 2) {
      #pragma unroll
      for (int g=0;g<4;g++) xsc[(w-2)*256 + g*64 + l] = acc[g];
    }
    __syncthreads();
    if (w < 2) {
      #pragma unroll
      for (int g=0;g<4;g++) acc[g] = acc[g] + xsc[w*256 + g*64 + l];
      int hcol = s*32 + c16*16 + (l&15);
      float* hdst = hbuf + (size_t)((t+1)&1)*HB + (size_t)grp*(16*512);
      bf16* hs = (bf16*)(ws + OFF_HS);
      #pragma unroll
      for (int rr=0; rr<4; rr++) {
        int row = (l>>4)*4 + rr;
        float iv = acc[0][rr] + (float)gxa[0][rr] + bias[0];
        float fv = acc[1][rr] + (float)gxa[1][rr] + bias[1];
        float gv = acc[2][rr] + (float)gxa[2][rr] + bias[2];
        float ov = acc[3][rr] + (float)gxa[3][rr] + bias[3];
        float ig = sigf(iv), fg = sigf(fv), gg = tanhf_(gv), og = sigf(ov);
        float cn = fg*c[rr] + ig*gg;
        c[rr] = cn;
        float hn = og * tanhf_(cn);
        __hip_atomic_store(hdst + (size_t)row*512 + hcol, hn,
                           __ATOMIC_RELAXED, __HIP_MEMORY_SCOPE_AGENT);
        int b = grp*16 + row;
        hs[((size_t)b*64 + t)*512 + hcol] = (bf16)hn;
      }
    }
    __syncthreads();
    if (t < 63 && tid == 0)
      __hip_atomic_fetch_add(cnt, 1u, __ATOMIC_RELEASE, __HIP_MEMORY_SCOPE_AGENT);
  }
}

// ---------------- temporal attention: logits partials (per t'), M=64/block ----------------
// grid (64 t, 4 mq), block 256
__global__ __launch_bounds__(256) void k_betapart(char* __restrict__ ws) {
  __shared__ __align__(16) char ldsA[8192];   // [64][64] bf16 swz
  __shared__ __align__(16) char ldsB[8192];   // [64][64] bf16 swz
  int t = blockIdx.x, mq = blockIdx.y;
  int tid = threadIdx.x, l = tid & 63, w = tid >> 6;
  const bf16* hsg = (const bf16*)(ws + OFF_HS);
  const char* wta = ws + OFF_WTA;
  f32x4 z = {0.f,0.f,0.f,0.f};
  f32x4 acc[4]; acc[0]=z; acc[1]=z; acc[2]=z; acc[3]=z;
  int row = tid >> 2, cq = tid & 3;
  for (int ksb=0; ksb<8; ksb++) {
    __syncthreads();
    {
      const bf16x8* src = (const bf16x8*)(hsg + ((size_t)(mq*64+row)*64 + t)*512 + ksb*64 + cq*16);
      u32 rb = (u32)(row*128), sw = ((u32)(row&7))<<4;
      *(bf16x8*)(ldsA + rb + (((u32)(cq*32))    ^ sw)) = src[0];
      *(bf16x8*)(ldsA + rb + (((u32)(cq*32+16)) ^ sw)) = src[1];
    }
    {
      const bf16x8* src = (const bf16x8*)(wta + 2*((size_t)row*32768 + t*512 + ksb*64 + cq*16));
      u32 rb = (u32)(row*128), sw = ((u32)(row&7))<<4;
      *(bf16x8*)(ldsB + rb + (((u32)(cq*32))    ^ sw)) = src[0];
      *(bf16x8*)(ldsB + rb + (((u32)(cq*32+16)) ^ sw)) = src[1];
    }
    __syncthreads();
    #pragma unroll
    for (int kk=0; kk<2; kk++) {
      int m = w*16 + (l&15);
      u32 abyte = (u32)(m*128) + (((u32)(kk*64 + ((l>>4)<<4))) ^ (((u32)(m&7))<<4));
      bf16x8 afr = *(const bf16x8*)(ldsA + abyte);
      #pragma unroll
      for (int j=0;j<4;j++) {
        int n = j*16 + (l&15);
        u32 bbyte = (u32)(n*128) + (((u32)(kk*64 + ((l>>4)<<4))) ^ (((u32)(n&7))<<4));
        bf16x8 bfr = *(const bf16x8*)(ldsB + bbyte);
        acc[j] = mfma16(afr, bfr, acc[j]);
      }
    }
  }
  float* outp = (float*)(ws + OFF_BPART) + (size_t)t*256*64;
  #pragma unroll
  for (int j=0;j<4;j++)
    #pragma unroll
    for (int rr=0;rr<4;rr++)
      outp[(size_t)(mq*64 + w*16 + (l>>4)*4 + rr)*64 + j*16 + (l&15)] = acc[j][rr];
}

// ---------------- pooled = sum_t beta*hs ; out = pooled @ W_out.T (+beta softmax fused) ----------------
__global__ __launch_bounds__(256) void k_pool(const float* __restrict__ bta,
                                              char* __restrict__ ws, float* __restrict__ out) {
  __shared__ float pooled[512];
  __shared__ float betas[64];
  int b = blockIdx.x, tid = threadIdx.x;
  if (tid < 64) {
    const float* part = (const float*)(ws + OFF_BPART);
    float v = 0.f;
    for (int t=0;t<64;t++) v += part[((size_t)t*256 + b)*64 + tid];
    v += bta[tid];
    v = fmaxf(v, 0.f);
    float mx = v;
    #pragma unroll
    for (int o=32;o>0;o>>=1) mx = fmaxf(mx, __shfl_xor(mx,o));
    float e = __expf(v - mx), sm = e;
    #pragma unroll
    for (int o=32;o>0;o>>=1) sm += __shfl_xor(sm,o);
    betas[tid] = e / sm;
  }
  __syncthreads();
  const bf16* hsb = (const bf16*)(ws + OFF_HS) + (size_t)b*64*512;
  float p0=0.f, p1=0.f;
  for (int t=0;t<64;t++) {
    float bw = betas[t];
    p0 += bw * (float)hsb[t*512 + tid];
    p1 += bw * (float)hsb[t*512 + 256 + tid];
  }
  pooled[tid] = p0; pooled[256+tid] = p1;
  __syncthreads();
  if (tid < 128) {
    const bf16* wo = (const bf16*)(ws + OFF_WOT);
    float a = 0.f;
    for (int j=0;j<512;j++) a += pooled[j] * (float)wo[j*128 + tid];
    out[(size_t)b*128 + tid] = a;
  }
}

// ---------------- launch ----------------
extern "C" void kernel_launch(void* const* d_in, const int* in_sizes, int n_in,
                              void* d_out, int out_size, void* d_ws, size_t ws_size,
                              hipStream_t stream) {
  (void)in_sizes; (void)n_in; (void)out_size; (void)ws_size;
  const float* input = (const float*)d_in[0];
  const float* gamma = (const float*)d_in[1];
  const float* betaP = (const float*)d_in[2];
  const float* Win   = (const float*)d_in[3];
  const float* Wsa   = (const float*)d_in[4];
  const float* bsa   = (const float*)d_in[5];
  const float* Wih   = (const float*)d_in[6];
  const float* Whh   = (const float*)d_in[7];
  const float* bih   = (const float*)d_in[8];
  const float* bhh   = (const float*)d_in[9];
  const float* Wta   = (const float*)d_in[10];
  const float* bta   = (const float*)d_in[11];
  const float* Wout  = (const float*)d_in[12];
  char* ws = (char*)d_ws;
  float* out = (float*)d_out;

  hipMemsetAsync(ws, 0, ZERO_END, stream);                    // stats, hbuf, counters
  k_prep    <<<1960, 256, 0, stream>>>(Whh, Wih, Wta, Wout, bih, bhh, input, ws);
  k_xnpack  <<<1024, 256, 0, stream>>>(input, gamma, betaP, ws);
  k_gemm1   <<<dim3(64,4), 512, 0, stream>>>(Win, ws);
  k_attn    <<<dim3(64,16), 256, 0, stream>>>(Wsa, bsa, ws);
  k_gxgemm  <<<dim3(256,16), 256, 0, stream>>>(ws);
  k_lstm    <<<256, 256, 0, stream>>>(ws);
  k_betapart<<<dim3(64,4), 256, 0, stream>>>(ws);
  k_pool    <<<256, 256, 0, stream>>>(bta, ws, out);
}

// Round 4
// 869.614 us; speedup vs baseline: 1.7641x; 1.7641x over previous
//
#include <hip/hip_runtime.h>
#include <hip/hip_bf16.h>

typedef __bf16 bf16;
typedef __bf16 bf16x8 __attribute__((ext_vector_type(8)));
typedef __bf16 bf16x4 __attribute__((ext_vector_type(4)));
typedef float  f32x4  __attribute__((ext_vector_type(4)));
typedef unsigned int u32;
typedef unsigned long long u64;

// ---------------- workspace layout (bytes), peak 120MB ----------------
#define OFF_BNSUM 0u
#define OFF_BNSQ  (32u<<10)
#define OFF_HBUF  (64u<<10)                       // 2 parity * 16 grp * 16 * 512 f32 = 1MB
#define OFF_CNT   ((64u<<10) + (1u<<20))          // 16 counters, 256B stride
#define ZERO_END  ((64u<<10) + (1u<<20) + 4096u)
#define OFF_XNP   (3u<<20)                        // xn packed frags bf16, 4MB
#define OFF_P     (8u<<20)                        // gemm1 partials 4*8MB (dead after k_attn)
#define OFF_HS    (8u<<20)                        // hs bf16 [256][64][512] 16MB (reuses P)
#define OFF_BPART (24u<<20)                       // beta partials f32 4MB (reuses P)
#define OFF_GATP  (40u<<20)                       // gated packed frags bf16 4MB
#define OFF_WIH   (44u<<20)                       // W_ih bf16 swizzled 512KB
#define OFF_WHH   (45u<<20)                       // W_hh packed frags bf16 2MB
#define OFF_BIAS2 (47u<<20)                       // b_ih+b_hh f32 8KB
#define OFF_WTA   (48u<<20)                       // W_ta bf16 4MB
#define OFF_WOT   (52u<<20)                       // W_out^T bf16 128KB
#define OFF_GX    (56u<<20)                       // gates_x packed bf16 64MB

__device__ __forceinline__ float sigf(float x){ return 1.0f/(1.0f+__expf(-x)); }
__device__ __forceinline__ float tanhf_(float x){
  x = fminf(fmaxf(x,-15.f),15.f);
  float e = __expf(2.f*x);
  return (e-1.f)/(e+1.f);
}
__device__ __forceinline__ f32x4 mfma16(bf16x8 a, bf16x8 b, f32x4 c){
  return __builtin_amdgcn_mfma_f32_16x16x32_bf16(a, b, c, 0, 0, 0);
}

// ---------------- prep: weight packing + BN partial stats ----------------
__global__ void k_prep(const float* __restrict__ Whh, const float* __restrict__ Wih,
                       const float* __restrict__ Wta, const float* __restrict__ Wout,
                       const float* __restrict__ bih, const float* __restrict__ bhh,
                       const float* __restrict__ input, char* __restrict__ ws) {
  if (blockIdx.x >= 1704) {             // BN partial stats
    int bxx = blockIdx.x - 1704;        // 256 blocks
    int col = (bxx >> 3)*256 + threadIdx.x;
    int r0 = (bxx & 7)*32;
    float s=0.f, s2=0.f;
    for (int r=0;r<32;r++){ float v = input[(size_t)(r0+r)*8192 + col]; s+=v; s2+=v*v; }
    float* wsf = (float*)ws;
    atomicAdd(&wsf[col], s);
    atomicAdd(&wsf[8192 + col], s2);
    return;
  }
  int tid = blockIdx.x*256 + threadIdx.x;
  if (tid < 16*8*16*64) {               // A: W_hh frag-pack, 131072 packs
    int l = tid & 63, kt = (tid>>6)&15, nt = (tid>>10)&7, s = tid>>13;
    int gate = nt>>1, c16 = nt&1;
    int n = gate*512 + s*32 + c16*16 + (l&15);
    int k0 = kt*32 + ((l>>4)<<3);
    const float* src = Whh + (size_t)n*512 + k0;
    bf16x8 v;
    #pragma unroll
    for (int j=0;j<8;j++) v[j] = (bf16)src[j];
    *(bf16x8*)(ws + OFF_WHH + (size_t)tid*16) = v;
    return;
  }
  int t2 = tid - 16*8*16*64;
  if (t2 < 2048*16) {                   // B: W_ih bf16 swizzled
    int n = t2 >> 4, kq = t2 & 15; int k0 = kq*8;
    const float* src = Wih + (size_t)n*128 + k0;
    bf16x8 v;
    #pragma unroll
    for (int j=0;j<8;j++) v[j] = (bf16)src[j];
    u32 byte = (u32)(n*256) + (((u32)(k0*2)) ^ (((u32)(n&7))<<4));
    *(bf16x8*)(ws + OFF_WIH + byte) = v;
    return;
  }
  int t3 = t2 - 2048*16;
  if (t3 < 262144) {                    // C: W_ta bf16
    const float* src = Wta + (size_t)t3*8;
    bf16x8 v;
    #pragma unroll
    for (int j=0;j<8;j++) v[j] = (bf16)src[j];
    *(bf16x8*)(ws + OFF_WTA + (size_t)t3*16) = v;
    return;
  }
  int t4 = t3 - 262144;
  if (t4 < 512*16) {                    // D: W_out^T bf16
    int j = t4 >> 4, oq = t4 & 15; int o0 = oq*8;
    bf16x8 v;
    #pragma unroll
    for (int jj=0;jj<8;jj++) v[jj] = (bf16)Wout[(size_t)(o0+jj)*512 + j];
    *(bf16x8*)(ws + OFF_WOT + (size_t)t4*16) = v;
    return;
  }
  int t5 = t4 - 8192;
  if (t5 < 2048) {                      // E: bias2
    ((float*)(ws + OFF_BIAS2))[t5] = bih[t5] + bhh[t5];
  }
}

// ---------------- xn = BN(input), packed into A-fragment layout ----------------
__global__ void k_xnpack(const float* __restrict__ in, const float* __restrict__ gamma,
                         const float* __restrict__ betaP, char* __restrict__ ws) {
  int idx = blockIdx.x*256 + threadIdx.x;   // 262144 items, grid 1024
  int l = idx & 63, kt = (idx>>6)&255, mt = idx>>14;
  int m = mt*16 + (l&15), k0 = kt*32 + ((l>>4)<<3);
  const float* sums = (const float*)(ws + OFF_BNSUM);
  const float* sqs  = (const float*)(ws + OFF_BNSQ);
  const float* src = in + (size_t)m*8192 + k0;
  bf16x8 v;
  #pragma unroll
  for (int j=0;j<8;j++) {
    int k = k0 + j;
    float mu = sums[k] * (1.f/256.f);
    float q  = sqs[k]  * (1.f/256.f);
    float rstd = rsqrtf(q - mu*mu + 1e-5f);
    float sc = rstd * gamma[k];
    v[j] = (bf16)(src[j]*sc + (betaP[k] - mu*sc));
  }
  *(bf16x8*)(ws + OFF_XNP + (size_t)idx*16) = v;
}

// ---------------- GEMM1: out1 = xn @ W_in.T  (M=256,N=8192,K=8192) ----------------
__global__ __launch_bounds__(512,2) void k_gemm1(const float* __restrict__ Win,
                                                 char* __restrict__ ws) {
  __shared__ __align__(16) char lds[2*16384];
  const int nb = blockIdx.x, ks = blockIdx.y;
  const int tid = threadIdx.x, l = tid & 63, w = tid >> 6;
  const int wm = w >> 1, wn = w & 1;
  const char* xnp = ws + OFF_XNP;
  f32x4 z = {0.f,0.f,0.f,0.f};
  f32x4 acc[4][4];
  #pragma unroll
  for (int i=0;i<4;i++){ acc[i][0]=z; acc[i][1]=z; acc[i][2]=z; acc[i][3]=z; }

  const int r = tid >> 2, kc = (tid & 3) << 4;
  const float* bsrc = Win + (size_t)(nb*128 + r)*8192 + ks*2048 + kc;
  const u32 sw = ((u32)(r&7))<<4;
  const u32 bdst0 = (u32)(r*128) + (((u32)(kc*2))     ^ sw);
  const u32 bdst1 = (u32)(r*128) + (((u32)(kc*2+16))  ^ sw);

  { // prologue stage step0
    f32x4 t0 = *(const f32x4*)(bsrc+0);
    f32x4 t1 = *(const f32x4*)(bsrc+4);
    f32x4 t2 = *(const f32x4*)(bsrc+8);
    f32x4 t3 = *(const f32x4*)(bsrc+12);
    bf16x8 p0,p1;
    #pragma unroll
    for(int j=0;j<4;j++){ p0[j]=(bf16)t0[j]; p0[4+j]=(bf16)t1[j]; p1[j]=(bf16)t2[j]; p1[4+j]=(bf16)t3[j]; }
    *(bf16x8*)(lds + bdst0) = p0;
    *(bf16x8*)(lds + bdst1) = p1;
  }
  int cur = 0;
  for (int s=0; s<32; s++) {
    f32x4 t0,t1,t2,t3;
    const bool more = (s+1) < 32;
    if (more) {
      const float* p = bsrc + (s+1)*64;
      t0 = *(const f32x4*)(p+0); t1 = *(const f32x4*)(p+4);
      t2 = *(const f32x4*)(p+8); t3 = *(const f32x4*)(p+12);
    }
    bf16x8 af[4][2];
    #pragma unroll
    for (int i=0;i<4;i++)
      #pragma unroll
      for (int kk=0;kk<2;kk++) {
        int mt = wm*4 + i;
        int ktg = ks*64 + s*2 + kk;
        af[i][kk] = *(const bf16x8*)(xnp + ((size_t)(mt*256 + ktg)*64 + l)*16);
      }
    __syncthreads();
    const char* buf = lds + cur*16384;
    bf16x8 bfr[4][2];
    #pragma unroll
    for (int j=0;j<4;j++)
      #pragma unroll
      for (int kk=0;kk<2;kk++) {
        int n = (wn*4 + j)*16 + (l&15);
        u32 byte = (u32)(n*128) + (((u32)(kk*64 + ((l>>4)<<4))) ^ (((u32)(n&7))<<4));
        bfr[j][kk] = *(const bf16x8*)(buf + byte);
      }
    #pragma unroll
    for (int kk=0;kk<2;kk++)
      #pragma unroll
      for (int i=0;i<4;i++)
        #pragma unroll
        for (int j=0;j<4;j++)
          acc[i][j] = mfma16(af[i][kk], bfr[j][kk], acc[i][j]);
    if (more) {
      bf16x8 p0,p1;
      #pragma unroll
      for(int j=0;j<4;j++){ p0[j]=(bf16)t0[j]; p0[4+j]=(bf16)t1[j]; p1[j]=(bf16)t2[j]; p1[4+j]=(bf16)t3[j]; }
      char* obuf = lds + (cur^1)*16384;
      *(bf16x8*)(obuf + bdst0) = p0;
      *(bf16x8*)(obuf + bdst1) = p1;
      cur ^= 1;
    }
  }
  float* outp = (float*)(ws + OFF_P) + (size_t)ks*256*8192;
  #pragma unroll
  for (int i=0;i<4;i++)
    #pragma unroll
    for (int j=0;j<4;j++)
      #pragma unroll
      for (int rr=0;rr<4;rr++) {
        int m = wm*64 + i*16 + (l>>4)*4 + rr;
        int n = nb*128 + (wn*4+j)*16 + (l&15);
        outp[(size_t)m*8192 + n] = acc[i][j][rr];
      }
}

// ---------------- spatial attention (+split-K reduce fused) -> gated, packed ----------------
__global__ __launch_bounds__(256) void k_attn(const float* __restrict__ Wsa,
                                              const float* __restrict__ bsa,
                                              char* __restrict__ ws) {
  __shared__ __align__(16) bf16 WsaT[128*128];   // [d][e] bf16, 32KB
  __shared__ __align__(16) float xrow[16*128];   // 8KB
  __shared__ __align__(16) bf16  gat[16*128];    // 4KB
  int t = blockIdx.x, bg = blockIdx.y;
  int tid = threadIdx.x, l = tid & 63, w = tid >> 6;
  for (int i = tid; i < 128*32; i += 256) {
    int e = i >> 5, dq = i & 31;
    f32x4 v = *(const f32x4*)(Wsa + (size_t)e*128 + dq*4);
    #pragma unroll
    for (int j=0;j<4;j++) WsaT[(dq*4+j)*128 + e] = (bf16)v[j];
  }
  const float* p0 = (const float*)(ws + OFF_P);
  const size_t SLAB = (size_t)256*8192;   // gemm1 partial slab stride, in floats (8MB)
  for (int i = tid; i < 16*32; i += 256) {
    int rb = i >> 5, dq = i & 31;
    size_t off = (size_t)(bg*16 + rb)*8192 + t*128 + dq*4;
    f32x4 v = *(const f32x4*)(p0 + off);
    v = v + *(const f32x4*)(p0 + SLAB   + off);
    v = v + *(const f32x4*)(p0 + 2*SLAB + off);
    v = v + *(const f32x4*)(p0 + 3*SLAB + off);
    *(f32x4*)(&xrow[rb*128 + dq*4]) = v;
  }
  __syncthreads();
  float b0 = bsa[l], b1 = bsa[64+l];
  for (int rb = w; rb < 16; rb += 4) {
    float a0 = b0, a1 = b1;
    const float* xr = &xrow[rb*128];
    #pragma unroll 4
    for (int d=0; d<128; d++) {
      float xv = xr[d];
      a0 += xv * (float)WsaT[d*128 + l];
      a1 += xv * (float)WsaT[d*128 + 64 + l];
    }
    a0 = sigf(a0); a1 = sigf(a1);
    float mx = fmaxf(a0,a1);
    #pragma unroll
    for (int o=32;o>0;o>>=1) mx = fmaxf(mx, __shfl_xor(mx,o));
    float e0 = __expf(a0-mx), e1 = __expf(a1-mx);
    float sm = e0+e1;
    #pragma unroll
    for (int o=32;o>0;o>>=1) sm += __shfl_xor(sm,o);
    float inv = 1.f/sm;
    gat[rb*128 + l]      = (bf16)(xr[l]     * e0*inv);
    gat[rb*128 + 64 + l] = (bf16)(xr[64+l]  * e1*inv);
  }
  __syncthreads();
  { // pack 16x128 tile into frag order
    int kt = tid >> 6;
    int m = l & 15, k0 = kt*32 + ((l>>4)<<3);
    bf16x8 v = *(const bf16x8*)(&gat[m*128 + k0]);
    *(bf16x8*)(ws + OFF_GATP + ((size_t)((t*16 + bg)*4 + kt)*64 + l)*16) = v;
  }
}

// ---------------- gates_x = gated @ W_ih.T, packed for LSTM ----------------
__global__ __launch_bounds__(256) void k_gxgemm(char* __restrict__ ws) {
  __shared__ __align__(16) char ldsB[32768];
  int mb = blockIdx.x, nb = blockIdx.y;
  int t = mb >> 2, bq = mb & 3;
  int tid = threadIdx.x, l = tid & 63, w = tid >> 6;
  int wm = w >> 1, wn = w & 1;
  {
    const f32x4* src = (const f32x4*)(ws + OFF_WIH + (size_t)nb*32768);
    f32x4* dst = (f32x4*)ldsB;
    for (int i = tid; i < 2048; i += 256) dst[i] = src[i];
  }
  __syncthreads();
  f32x4 z = {0.f,0.f,0.f,0.f};
  f32x4 acc[2][4];
  #pragma unroll
  for (int i=0;i<2;i++){ acc[i][0]=z; acc[i][1]=z; acc[i][2]=z; acc[i][3]=z; }
  const char* gatp = ws + OFF_GATP;
  #pragma unroll
  for (int kt=0; kt<4; kt++) {
    bf16x8 a[2], bb[4];
    #pragma unroll
    for (int i=0;i<2;i++) {
      int mtg = bq*4 + wm*2 + i;
      a[i] = *(const bf16x8*)(gatp + ((size_t)((t*16 + mtg)*4 + kt)*64 + l)*16);
    }
    #pragma unroll
    for (int j=0;j<4;j++) {
      int n = (wn*4 + j)*16 + (l&15);
      u32 byte = (u32)(n*256) + (((u32)(kt*64 + ((l>>4)<<4))) ^ (((u32)(n&7))<<4));
      bb[j] = *(const bf16x8*)(ldsB + byte);
    }
    #pragma unroll
    for (int i=0;i<2;i++)
      #pragma unroll
      for (int j=0;j<4;j++)
        acc[i][j] = mfma16(a[i], bb[j], acc[i][j]);
  }
  int gate = nb >> 2, q = nb & 3;
  #pragma unroll
  for (int i=0;i<2;i++)
    #pragma unroll
    for (int j=0;j<4;j++) {
      int ntl = wn*4 + j;
      int c16g = q*8 + ntl;
      int s = c16g >> 1, c16 = c16g & 1;
      int nt_out = gate*2 + c16;
      int mtg = bq*4 + wm*2 + i;           // == batch group
      bf16x4 pv;
      #pragma unroll
      for (int rr=0;rr<4;rr++) pv[rr] = (bf16)acc[i][j][rr];
      *(bf16x4*)(ws + OFF_GX + (((((size_t)mtg*64 + t)*16 + s)*8 + nt_out)*64 + l)*8) = pv;
    }
}

// ---------------- LSTM: 256 blocks = 16 groups x 16 H-slices; W_hh in VGPRs ----------------
// Cross-block protocol: ALL cross-block data (hbuf, cnt) uses RELAXED agent-scope
// atomics only (-> sc1 loads/stores served by L3, no L2 staleness). Ordering via
// vmcnt(0)+barrier before the relaxed counter add. NO acquire/release fences:
// agent fences emit buffer_inv/buffer_wbl2 (full-L2 invalidate/writeback) which
// cost ~15us/step (round-3 counters: MfmaUtil 1.4%, 999us).
__global__ __launch_bounds__(256,1) void k_lstm(char* __restrict__ ws) {
  __shared__ __align__(16) char hl[16*1024];   // h tile [16][512] bf16, XOR-swizzled
  __shared__ __align__(16) f32x4 xsc[512];     // cross-wave acc exchange
  const int bid = blockIdx.x;
  const int grp = bid & 15, s = bid >> 4;      // grp=bid&15: group's 16 blocks share XCD under round-robin
  const int tid = threadIdx.x, l = tid & 63, w = tid >> 6;
  const int c16 = w & 1, kh = w >> 1;
  bf16x8 breg[4][8];
  {
    const char* wp = ws + OFF_WHH;
    #pragma unroll
    for (int g=0; g<4; g++) {
      int nt = g*2 + c16;
      #pragma unroll
      for (int j=0;j<8;j++) {
        int kt = kh*8 + j;
        breg[g][j] = *(const bf16x8*)(wp + ((size_t)((s*8 + nt)*16 + kt)*64 + l)*16);
      }
    }
  }
  float bias[4] = {0,0,0,0};
  if (w < 2) {
    const float* b2 = (const float*)(ws + OFF_BIAS2);
    #pragma unroll
    for (int g=0;g<4;g++) bias[g] = b2[g*512 + s*32 + c16*16 + (l&15)];
  }
  float c[4] = {0,0,0,0};
  u32* cnt = (u32*)(ws + OFF_CNT) + grp*64;
  float* hbuf = (float*)(ws + OFF_HBUF);
  const int HB = 16*16*512;
  const int lrow = tid >> 4, lq = tid & 15;    // LDS-fill mapping
  const char* gx = ws + OFF_GX;

  for (int t=0; t<64; t++) {
    // gx fragments are immutable inputs: issue loads BEFORE the spin so their
    // latency hides under the wait.
    bf16x4 gxa[4];
    if (w < 2) {
      #pragma unroll
      for (int g=0;g<4;g++) {
        int nt = g*2 + c16;
        gxa[g] = *(const bf16x4*)(gx + (((((size_t)grp*64 + t)*16 + s)*8 + nt)*64 + l)*8);
      }
    }
    if (t > 0) {
      // lane0 of EACH wave spins (no extra barrier needed: wave reconverges,
      // subsequent loads are program-order after the satisfying poll)
      if (l == 0) {
        u32 target = (u32)(16*t);
        while (__hip_atomic_load(cnt, __ATOMIC_RELAXED, __HIP_MEMORY_SCOPE_AGENT) < target)
          __builtin_amdgcn_s_sleep(1);
      }
    }
    { // fill LDS h tile via sc1 (agent-coherent) u64 loads; conflict-free swizzled b64 writes
      const u64* hp = (const u64*)(hbuf + (size_t)(t&1)*HB + (size_t)grp*(16*512));
      u32 base = (u32)(lrow*1024);
      u32 swz = ((u32)(lrow&7)) << 4;
      #pragma unroll
      for (int i=0;i<8;i++) {
        int fo = lrow*256 + lq*2 + i*32;   // u64 index: cols lq*4+i*64 .. +3
        u64 v01 = __hip_atomic_load(hp+fo,   __ATOMIC_RELAXED, __HIP_MEMORY_SCOPE_AGENT);
        u64 v23 = __hip_atomic_load(hp+fo+1, __ATOMIC_RELAXED, __HIP_MEMORY_SCOPE_AGENT);
        bf16x4 pv;
        pv[0] = (bf16)__uint_as_float((u32)v01);
        pv[1] = (bf16)__uint_as_float((u32)(v01>>32));
        pv[2] = (bf16)__uint_as_float((u32)v23);
        pv[3] = (bf16)__uint_as_float((u32)(v23>>32));
        u32 byte = base + (((u32)(lq*8 + i*128)) ^ swz);
        *(bf16x4*)(hl + byte) = pv;
      }
    }
    __syncthreads();
    f32x4 z = {0.f,0.f,0.f,0.f};
    f32x4 acc[4]; acc[0]=z; acc[1]=z; acc[2]=z; acc[3]=z;
    {
      bf16x8 af[8];
      u32 qof = ((u32)(l>>4)) << 4;
      int row = l & 15;
      u32 rsw = ((u32)(row&7))<<4;
      #pragma unroll
      for (int j=0;j<8;j++) {
        int kt = kh*8 + j;
        u32 byte = (u32)(row*1024) + ((((u32)(kt*64)) + qof) ^ rsw);
        af[j] = *(const bf16x8*)(hl + byte);
      }
      #pragma unroll
      for (int j=0;j<8;j++)
        #pragma unroll
        for (int g=0;g<4;g++)
          acc[g] = mfma16(af[j], breg[g][j], acc[g]);
    }
    if (w >= 2) {
      #pragma unroll
      for (int g=0;g<4;g++) xsc[(w-2)*256 + g*64 + l] = acc[g];
    }
    __syncthreads();
    if (w < 2) {
      #pragma unroll
      for (int g=0;g<4;g++) acc[g] = acc[g] + xsc[w*256 + g*64 + l];
      int hcol = s*32 + c16*16 + (l&15);
      float* hdst = hbuf + (size_t)((t+1)&1)*HB + (size_t)grp*(16*512);
      bf16* hs = (bf16*)(ws + OFF_HS);
      #pragma unroll
      for (int rr=0; rr<4; rr++) {
        int row = (l>>4)*4 + rr;
        float iv = acc[0][rr] + (float)gxa[0][rr] + bias[0];
        float fv = acc[1][rr] + (float)gxa[1][rr] + bias[1];
        float gv = acc[2][rr] + (float)gxa[2][rr] + bias[2];
        float ov = acc[3][rr] + (float)gxa[3][rr] + bias[3];
        float ig = sigf(iv), fg = sigf(fv), gg = tanhf_(gv), og = sigf(ov);
        float cn = fg*c[rr] + ig*gg;
        c[rr] = cn;
        float hn = og * tanhf_(cn);
        __hip_atomic_store(hdst + (size_t)row*512 + hcol, hn,
                           __ATOMIC_RELAXED, __HIP_MEMORY_SCOPE_AGENT);
        int b = grp*16 + row;
        hs[((size_t)b*64 + t)*512 + hcol] = (bf16)hn;
      }
      // ensure this wave's sc1 h-stores are at the coherence point before the
      // barrier that gates the counter add (wave-uniform branch -> safe)
      asm volatile("s_waitcnt vmcnt(0)" ::: "memory");
    }
    __syncthreads();
    if (t < 63 && tid == 0)
      __hip_atomic_fetch_add(cnt, 1u, __ATOMIC_RELAXED, __HIP_MEMORY_SCOPE_AGENT);
  }
}

// ---------------- temporal attention: logits partials (per t'), M=64/block ----------------
__global__ __launch_bounds__(256) void k_betapart(char* __restrict__ ws) {
  __shared__ __align__(16) char ldsA[8192];   // [64][64] bf16 swz
  __shared__ __align__(16) char ldsB[8192];   // [64][64] bf16 swz
  int t = blockIdx.x, mq = blockIdx.y;
  int tid = threadIdx.x, l = tid & 63, w = tid >> 6;
  const bf16* hsg = (const bf16*)(ws + OFF_HS);
  const char* wta = ws + OFF_WTA;
  f32x4 z = {0.f,0.f,0.f,0.f};
  f32x4 acc[4]; acc[0]=z; acc[1]=z; acc[2]=z; acc[3]=z;
  int row = tid >> 2, cq = tid & 3;
  for (int ksb=0; ksb<8; ksb++) {
    __syncthreads();
    {
      const bf16x8* src = (const bf16x8*)(hsg + ((size_t)(mq*64+row)*64 + t)*512 + ksb*64 + cq*16);
      u32 rb = (u32)(row*128), sw = ((u32)(row&7))<<4;
      *(bf16x8*)(ldsA + rb + (((u32)(cq*32))    ^ sw)) = src[0];
      *(bf16x8*)(ldsA + rb + (((u32)(cq*32+16)) ^ sw)) = src[1];
    }
    {
      const bf16x8* src = (const bf16x8*)(wta + 2*((size_t)row*32768 + t*512 + ksb*64 + cq*16));
      u32 rb = (u32)(row*128), sw = ((u32)(row&7))<<4;
      *(bf16x8*)(ldsB + rb + (((u32)(cq*32))    ^ sw)) = src[0];
      *(bf16x8*)(ldsB + rb + (((u32)(cq*32+16)) ^ sw)) = src[1];
    }
    __syncthreads();
    #pragma unroll
    for (int kk=0; kk<2; kk++) {
      int m = w*16 + (l&15);
      u32 abyte = (u32)(m*128) + (((u32)(kk*64 + ((l>>4)<<4))) ^ (((u32)(m&7))<<4));
      bf16x8 afr = *(const bf16x8*)(ldsA + abyte);
      #pragma unroll
      for (int j=0;j<4;j++) {
        int n = j*16 + (l&15);
        u32 bbyte = (u32)(n*128) + (((u32)(kk*64 + ((l>>4)<<4))) ^ (((u32)(n&7))<<4));
        bf16x8 bfr = *(const bf16x8*)(ldsB + bbyte);
        acc[j] = mfma16(afr, bfr, acc[j]);
      }
    }
  }
  float* outp = (float*)(ws + OFF_BPART) + (size_t)t*256*64;
  #pragma unroll
  for (int j=0;j<4;j++)
    #pragma unroll
    for (int rr=0;rr<4;rr++)
      outp[(size_t)(mq*64 + w*16 + (l>>4)*4 + rr)*64 + j*16 + (l&15)] = acc[j][rr];
}

// ---------------- pooled = sum_t beta*hs ; out = pooled @ W_out.T (+beta softmax fused) ----------------
__global__ __launch_bounds__(256) void k_pool(const float* __restrict__ bta,
                                              char* __restrict__ ws, float* __restrict__ out) {
  __shared__ float pooled[512];
  __shared__ float betas[64];
  int b = blockIdx.x, tid = threadIdx.x;
  if (tid < 64) {
    const float* part = (const float*)(ws + OFF_BPART);
    float v = 0.f;
    for (int t=0;t<64;t++) v += part[((size_t)t*256 + b)*64 + tid];
    v += bta[tid];
    v = fmaxf(v, 0.f);
    float mx = v;
    #pragma unroll
    for (int o=32;o>0;o>>=1) mx = fmaxf(mx, __shfl_xor(mx,o));
    float e = __expf(v - mx), sm = e;
    #pragma unroll
    for (int o=32;o>0;o>>=1) sm += __shfl_xor(sm,o);
    betas[tid] = e / sm;
  }
  __syncthreads();
  const bf16* hsb = (const bf16*)(ws + OFF_HS) + (size_t)b*64*512;
  float p0=0.f, p1=0.f;
  for (int t=0;t<64;t++) {
    float bw = betas[t];
    p0 += bw * (float)hsb[t*512 + tid];
    p1 += bw * (float)hsb[t*512 + 256 + tid];
  }
  pooled[tid] = p0; pooled[256+tid] = p1;
  __syncthreads();
  if (tid < 128) {
    const bf16* wo = (const bf16*)(ws + OFF_WOT);
    float a = 0.f;
    for (int j=0;j<512;j++) a += pooled[j] * (float)wo[j*128 + tid];
    out[(size_t)b*128 + tid] = a;
  }
}

// ---------------- launch ----------------
extern "C" void kernel_launch(void* const* d_in, const int* in_sizes, int n_in,
                              void* d_out, int out_size, void* d_ws, size_t ws_size,
                              hipStream_t stream) {
  (void)in_sizes; (void)n_in; (void)out_size; (void)ws_size;
  const float* input = (const float*)d_in[0];
  const float* gamma = (const float*)d_in[1];
  const float* betaP = (const float*)d_in[2];
  const float* Win   = (const float*)d_in[3];
  const float* Wsa   = (const float*)d_in[4];
  const float* bsa   = (const float*)d_in[5];
  const float* Wih   = (const float*)d_in[6];
  const float* Whh   = (const float*)d_in[7];
  const float* bih   = (const float*)d_in[8];
  const float* bhh   = (const float*)d_in[9];
  const float* Wta   = (const float*)d_in[10];
  const float* bta   = (const float*)d_in[11];
  const float* Wout  = (const float*)d_in[12];
  char* ws = (char*)d_ws;
  float* out = (float*)d_out;

  hipMemsetAsync(ws, 0, ZERO_END, stream);                    // stats, hbuf, counters
  k_prep    <<<1960, 256, 0, stream>>>(Whh, Wih, Wta, Wout, bih, bhh, input, ws);
  k_xnpack  <<<1024, 256, 0, stream>>>(input, gamma, betaP, ws);
  k_gemm1   <<<dim3(64,4), 512, 0, stream>>>(Win, ws);
  k_attn    <<<dim3(64,16), 256, 0, stream>>>(Wsa, bsa, ws);
  k_gxgemm  <<<dim3(256,16), 256, 0, stream>>>(ws);
  k_lstm    <<<256, 256, 0, stream>>>(ws);
  k_betapart<<<dim3(64,4), 256, 0, stream>>>(ws);
  k_pool    <<<256, 256, 0, stream>>>(bta, ws, out);
}